// Round 6
// baseline (210.636 us; speedup 1.0000x reference)
//
#include <hip/hip_runtime.h>
#include <math.h>

#define BATCH  32768
#define D      128
#define K      6400
#define KC     64
#define ROWS_PER_BLOCK 64
#define GROUPS_PER_WAVE 25     // 25 groups of 64 centers = 1600 per quarter

typedef _Float16 half8 __attribute__((ext_vector_type(8)));
typedef float    floatx4 __attribute__((ext_vector_type(4)));

// ---- pack centers to fp16 (group-major) + c2n = -0.5*||c||^2 ----
// 16B unit n = g*1024 + u*64 + cw holds center (g*64+cw), k in [u*8, u*8+8).
__global__ __launch_bounds__(256) void pack_kernel(const float* __restrict__ centers,
                                                   _Float16* __restrict__ wh,
                                                   float* __restrict__ c2n) {
    int tid = blockIdx.x * 256 + threadIdx.x;   // 0 .. K*16-1
    int g  = tid >> 10;
    int u  = (tid >> 6) & 15;
    int cw = tid & 63;
    int center = g * 64 + cw;
    const float* src = centers + (size_t)center * D + u * 8;
    float4 a = *(const float4*)src;
    float4 b = *(const float4*)(src + 4);
    float f[8] = {a.x, a.y, a.z, a.w, b.x, b.y, b.z, b.w};
    half8 h;
#pragma unroll
    for (int j = 0; j < 8; ++j) h[j] = (_Float16)f[j];
    *(half8*)(wh + (size_t)tid * 8) = h;

    // fused c2n: blocks 0..99 each cover 64 centers, 4 threads per center
    if (blockIdx.x < K / KC) {
        int c_local = threadIdx.x >> 2, part = threadIdx.x & 3;
        int c = blockIdx.x * 64 + c_local;
        const float4* p = (const float4*)(centers + (size_t)c * D + part * 32);
        float s = 0.f;
#pragma unroll
        for (int i = 0; i < 8; ++i) {
            float4 v = p[i];
            s = fmaf(v.x, v.x, s); s = fmaf(v.y, v.y, s);
            s = fmaf(v.z, v.z, s); s = fmaf(v.w, v.w, s);
        }
        s += __shfl_xor(s, 1, 64);
        s += __shfl_xor(s, 2, 64);
        if (part == 0) c2n[c] = -0.5f * s;
    }
}

// ---- fused distance + argmin kernel, barrier-free K-loop ----
// Block: 512 threads = 8 waves = 2 rowhalves x 4 center-quarters; block owns
// 64 rows x ALL 6400 centers (fused epilogue, no merge kernel).
// B (1.6 MB fp16, L2-resident) is read DIRECTLY from global into VGPRs —
// no LDS staging, no __syncthreads in the K-loop. Latency hidden by 4 waves/SIMD
// (grid 512 = 2 blocks/CU) + in-flight load batches.
// Scores: max of (dot - c2/2); best-2 per (row, 800-center stream); exact fp32
// refine of 16 candidates/row at the end.
__global__ __launch_bounds__(512, 4) void dist_kernel(
    const float* __restrict__ x, const float* __restrict__ centers,
    const _Float16* __restrict__ wh, const float* __restrict__ c2n,
    float* __restrict__ out) {
    __shared__ int candL[ROWS_PER_BLOCK * 16];
    __shared__ int winL[ROWS_PER_BLOCK];

    const int t    = threadIdx.x;
    const int w    = t >> 6;
    const int L    = t & 63;
    const int quad = L >> 4;
    const int n16  = L & 15;
    const int rowhalf = w & 1;
    const int q       = w >> 1;          // center quarter 0..3
    const int gr0  = blockIdx.x * ROWS_PER_BLOCK;

    // ---- preload A fragments (this wave's 32 rows, all 128 k, fp16) ----
    half8 Ah[2][4];
#pragma unroll
    for (int rt = 0; rt < 2; ++rt) {
        int r = gr0 + rowhalf * 32 + rt * 16 + n16;
        const float* xr = x + (size_t)r * D + quad * 8;
#pragma unroll
        for (int ks = 0; ks < 4; ++ks) {
            float4 a = *(const float4*)(xr + ks * 32);
            float4 b = *(const float4*)(xr + ks * 32 + 4);
            float f[8] = {a.x, a.y, a.z, a.w, b.x, b.y, b.z, b.w};
            half8 h;
#pragma unroll
            for (int j = 0; j < 8; ++j) h[j] = (_Float16)f[j];
            Ah[rt][ks] = h;
        }
    }

    // best-2 (max of dot - c2/2) per slot k = rt*4+reg
    float b1[8], b2[8];
    int   j1_[8], j2_[8];
#pragma unroll
    for (int k = 0; k < 8; ++k) { b1[k] = -3.4e38f; b2[k] = -3.4e38f; j1_[k] = 0; j2_[k] = 0; }

    // wave's B stream: groups q*25 .. q*25+24 (64 centers each)
    const half8* pw = (const half8*)wh + ((size_t)q * GROUPS_PER_WAVE) * 1024 + quad * 64 + n16;
    const float* pc = c2n + q * GROUPS_PER_WAVE * 64 + n16;

    for (int ci = 0; ci < GROUPS_PER_WAVE; ++ci) {
        floatx4 acc[2][4];
#pragma unroll
        for (int rt = 0; rt < 2; ++rt)
#pragma unroll
            for (int ct = 0; ct < 4; ++ct) acc[rt][ct] = (floatx4){0.f, 0.f, 0.f, 0.f};

        float c2v[4];
#pragma unroll
        for (int ct = 0; ct < 4; ++ct) c2v[ct] = pc[ci * 64 + ct * 16];

        const half8* pg = pw + ci * 1024;
#pragma unroll
        for (int ks = 0; ks < 4; ++ks) {
            half8 Bf[4];
#pragma unroll
            for (int ct = 0; ct < 4; ++ct) Bf[ct] = pg[ks * 256 + ct * 16];
#pragma unroll
            for (int ct = 0; ct < 4; ++ct) {
                acc[0][ct] = __builtin_amdgcn_mfma_f32_16x16x32_f16(Ah[0][ks], Bf[ct], acc[0][ct], 0, 0, 0);
                acc[1][ct] = __builtin_amdgcn_mfma_f32_16x16x32_f16(Ah[1][ks], Bf[ct], acc[1][ct], 0, 0, 0);
            }
        }

        // quad-reduce over ct (same row), then best-2 insert per slot.
        int i0 = (q * GROUPS_PER_WAVE + ci) * 64 + n16;
#pragma unroll
        for (int rt = 0; rt < 2; ++rt)
#pragma unroll
            for (int reg = 0; reg < 4; ++reg) {
                float s0 = acc[rt][0][reg] + c2v[0];
                float s1 = acc[rt][1][reg] + c2v[1];
                float s2 = acc[rt][2][reg] + c2v[2];
                float s3 = acc[rt][3][reg] + c2v[3];
                bool g01 = s1 > s0, g23 = s3 > s2;
                float m01 = g01 ? s1 : s0;  int x01 = g01 ? i0 + 16 : i0;
                float m23 = g23 ? s3 : s2;  int x23 = g23 ? i0 + 48 : i0 + 32;
                bool gq = m23 > m01;
                float v  = gq ? m23 : m01;  int vi = gq ? x23 : x01;
                int k = rt * 4 + reg;
                bool bet1 = v > b1[k];
                bool bet2 = v > b2[k];
                float nb2 = bet1 ? b1[k] : (bet2 ? v : b2[k]);
                int   nj2 = bet1 ? j1_[k] : (bet2 ? vi : j2_[k]);
                b1[k]  = bet1 ? v : b1[k];
                j1_[k] = bet1 ? vi : j1_[k];
                b2[k]  = nb2;
                j2_[k] = nj2;
            }
    }

    // merge sorted best-2 (max) across 8-lane n16 halves -> best-2 per 800-center stream
#pragma unroll
    for (int k = 0; k < 8; ++k) {
        float v1 = b1[k], v2 = b2[k];
        int   p1 = j1_[k], p2 = j2_[k];
#pragma unroll
        for (int m = 1; m < 8; m <<= 1) {
            float o1 = __shfl_xor(v1, m, 64), o2 = __shfl_xor(v2, m, 64);
            int   q1 = __shfl_xor(p1, m, 64), q2 = __shfl_xor(p2, m, 64);
            bool firstMine = (v1 > o1) || (v1 == o1 && p1 < q1);
            float nv1 = firstMine ? v1 : o1;  int np1 = firstMine ? p1 : q1;
            float cb  = firstMine ? o1 : v1;  int cpi = firstMine ? q1 : p1;  // loser of firsts
            float ob  = firstMine ? v2 : o2;  int obi = firstMine ? p2 : q2;  // winner's own 2nd
            bool secOwn = (ob > cb) || (ob == cb && obi < cpi);
            v1 = nv1; p1 = np1;
            v2 = secOwn ? ob : cb;  p2 = secOwn ? obi : cpi;
        }
        if ((n16 & 7) == 0) {
            int rloc = rowhalf * 32 + (k >> 2) * 16 + quad * 4 + (k & 3);
            int col = q * 4 + (n16 >> 3) * 2;
            candL[rloc * 16 + col + 0] = p1;
            candL[rloc * 16 + col + 1] = p2;
        }
    }
    __syncthreads();

    float* out_q   = out;
    float* out_clu = out + (size_t)BATCH * D;
    float* out_md  = out_clu + BATCH;
    float* out_cls = out_md + BATCH;

    // exact fp32 refine: 16 candidates/row, 2 per thread (64 rows x 8 threads)
    {
        int r = t >> 3, p = t & 7;
        int ixa = candL[r * 16 + p * 2 + 0];
        int ixb = candL[r * 16 + p * 2 + 1];
        const float4* xr4 = (const float4*)(x + (size_t)(gr0 + r) * D);
        const float4* ca4 = (const float4*)(centers + (size_t)ixa * D);
        const float4* cb4 = (const float4*)(centers + (size_t)ixb * D);
        float dota = 0.f, dotb = 0.f, x2s = 0.f, c2a = 0.f, c2b = 0.f;
#pragma unroll
        for (int d4 = 0; d4 < 32; ++d4) {
            float4 xv = xr4[d4], av = ca4[d4], bv = cb4[d4];
            dota = fmaf(xv.x, av.x, dota); dota = fmaf(xv.y, av.y, dota);
            dota = fmaf(xv.z, av.z, dota); dota = fmaf(xv.w, av.w, dota);
            dotb = fmaf(xv.x, bv.x, dotb); dotb = fmaf(xv.y, bv.y, dotb);
            dotb = fmaf(xv.z, bv.z, dotb); dotb = fmaf(xv.w, bv.w, dotb);
            x2s = fmaf(xv.x, xv.x, x2s); x2s = fmaf(xv.y, xv.y, x2s);
            x2s = fmaf(xv.z, xv.z, x2s); x2s = fmaf(xv.w, xv.w, x2s);
            c2a = fmaf(av.x, av.x, c2a); c2a = fmaf(av.y, av.y, c2a);
            c2a = fmaf(av.z, av.z, c2a); c2a = fmaf(av.w, av.w, c2a);
            c2b = fmaf(bv.x, bv.x, c2b); c2b = fmaf(bv.y, bv.y, c2b);
            c2b = fmaf(bv.z, bv.z, c2b); c2b = fmaf(bv.w, bv.w, c2b);
        }
        float sqa = x2s + c2a - 2.f * dota;
        float sqb = x2s + c2b - 2.f * dotb;
        bool aw = (sqa < sqb) || (sqa == sqb && ixa < ixb);
        float sq = aw ? sqa : sqb;
        int   ix = aw ? ixa : ixb;
#pragma unroll
        for (int m = 1; m < 8; m <<= 1) {
            float osq = __shfl_xor(sq, m, 64);
            int   oix = __shfl_xor(ix, m, 64);
            if (osq < sq || (osq == sq && oix < ix)) { sq = osq; ix = oix; }
        }
        if (p == 0) {
            out_md[gr0 + r]  = sqrtf(fmaxf(sq, 0.f));
            out_clu[gr0 + r] = (float)(ix & (KC - 1));
            out_cls[gr0 + r] = (float)(ix >> 6);
            winL[r] = ix;
        }
    }
    __syncthreads();

    // quantized = x + (c - x), coalesced
    {
        const float4* cg4 = (const float4*)centers;
        const float4* xg4 = (const float4*)x + (size_t)gr0 * 32;
        float4* oq4 = (float4*)out_q + (size_t)gr0 * 32;
#pragma unroll
        for (int p = 0; p < 4; ++p) {
            int lin = p * 512 + t;
            int r = lin >> 5, d4 = lin & 31;
            int ix = winL[r];
            float4 cv = cg4[(size_t)ix * 32 + d4];
            float4 xv = xg4[lin];
            float4 o;
            o.x = xv.x + (cv.x - xv.x);
            o.y = xv.y + (cv.y - xv.y);
            o.z = xv.z + (cv.z - xv.z);
            o.w = xv.w + (cv.w - xv.w);
            oq4[lin] = o;
        }
    }
}

extern "C" void kernel_launch(void* const* d_in, const int* in_sizes, int n_in,
                              void* d_out, int out_size, void* d_ws, size_t ws_size,
                              hipStream_t stream) {
    const float* x       = (const float*)d_in[0];
    const float* centers = (const float*)d_in[1];
    // d_in[2] = labels (int64) — unused by the forward computation
    float* out = (float*)d_out;

    _Float16* wh  = (_Float16*)d_ws;                // K*D halves, group-major
    float*    c2n = (float*)(wh + (size_t)K * D);   // -0.5*||c||^2, K floats

    pack_kernel<<<(K * 16) / 256, 256, 0, stream>>>(centers, wh, c2n);
    dist_kernel<<<BATCH / ROWS_PER_BLOCK, 512, 0, stream>>>(x, centers, wh, c2n, out);
}

// Round 7
// 197.104 us; speedup vs baseline: 1.0687x; 1.0687x over previous
//
#include <hip/hip_runtime.h>
#include <math.h>

#define BATCH  32768
#define D      128
#define K      6400
#define KC     64
#define ROWS_PER_BLOCK 128
#define CHUNK_C 128
#define HALVES 2
#define CHUNKS_PER_HALF 25            // 25 * 128 * 2 halves = 6400

typedef _Float16 half8 __attribute__((ext_vector_type(8)));
typedef float    floatx4 __attribute__((ext_vector_type(4)));

typedef __attribute__((address_space(3))) unsigned       lds_uint;
typedef __attribute__((address_space(1))) const unsigned glb_uint;

__device__ __forceinline__ void async_lds16(const void* g, void* l) {
    __builtin_amdgcn_global_load_lds((glb_uint*)g, (lds_uint*)l, 16, 0, 0);
}

// ---- pack centers to fp16 (chunk-major for global_load_lds) + c2n = -0.5*||c||^2 ----
// 16B unit n = ch*2048 + u*128 + cw  holds center (ch*128+cw), k in [u*8, u*8+8).
__global__ __launch_bounds__(256) void pack_kernel(const float* __restrict__ centers,
                                                   _Float16* __restrict__ wh,
                                                   float* __restrict__ c2n) {
    int tid = blockIdx.x * 256 + threadIdx.x;   // 0 .. K*16-1
    int ch = tid >> 11;
    int u  = (tid >> 7) & 15;
    int cw = tid & 127;
    int center = ch * CHUNK_C + cw;
    const float* src = centers + (size_t)center * D + u * 8;
    float4 a = *(const float4*)src;
    float4 b = *(const float4*)(src + 4);
    float f[8] = {a.x, a.y, a.z, a.w, b.x, b.y, b.z, b.w};
    half8 h;
#pragma unroll
    for (int j = 0; j < 8; ++j) h[j] = (_Float16)f[j];
    *(half8*)(wh + (size_t)tid * 8) = h;

    // fused c2n: blocks 0..99 each cover 64 centers, 4 threads per center
    if (blockIdx.x < K / KC) {
        int c_local = threadIdx.x >> 2, part = threadIdx.x & 3;
        int c = blockIdx.x * 64 + c_local;
        const float4* p = (const float4*)(centers + (size_t)c * D + part * 32);
        float s = 0.f;
#pragma unroll
        for (int i = 0; i < 8; ++i) {
            float4 v = p[i];
            s = fmaf(v.x, v.x, s); s = fmaf(v.y, v.y, s);
            s = fmaf(v.z, v.z, s); s = fmaf(v.w, v.w, s);
        }
        s += __shfl_xor(s, 1, 64);
        s += __shfl_xor(s, 2, 64);
        if (part == 0) c2n[c] = -0.5f * s;
    }
}

// ---- distance + candidate kernel: double-buffered LDS, 1 barrier per chunk ----
// Block: 512 threads = 8 waves = 4 rowquarters x 2 centerhalves; 128 rows/block.
// Wave tile 32 rows x 64 centers (rt=2, ct=4 — the proven R4 shape).
// K-loop: issue async global_load_lds for chunk ci+1 into buf[(ci+1)&1], THEN
// compute chunk ci from buf[ci&1], then ONE __syncthreads. The barrier's implicit
// vmcnt(0) drain is ~free because the prefetch had the whole compute phase in
// flight — this is the async-pipeline shape the 2-barrier loop can't express.
// Center-split over blockIdx.y (2 halves); exact fp32 refine of 8 cand/row;
// (sq, idx) to ws; final_kernel merges halves + writes all outputs.
__global__ __launch_bounds__(512, 4) void dist_kernel(
    const float* __restrict__ x, const float* __restrict__ centers,
    const _Float16* __restrict__ wh, const float* __restrict__ c2n,
    float* __restrict__ ws_sq, int* __restrict__ ws_ix) {
    __shared__ char lds[65536];   // two 32 KB chunk buffers; aliased in epilogue

    const int t    = threadIdx.x;
    const int w    = t >> 6;
    const int L    = t & 63;
    const int quad = L >> 4;
    const int n16  = L & 15;
    const int rq      = w >> 1;   // row quarter 0..3
    const int chalf   = w & 1;    // center half of chunk
    const int half = blockIdx.y;
    const int gr0  = blockIdx.x * ROWS_PER_BLOCK;

    // ---- preload A fragments (this wave's 32 rows, all 128 k, fp16) ----
    half8 Ah[2][4];
#pragma unroll
    for (int rt = 0; rt < 2; ++rt) {
        int r = gr0 + rq * 32 + rt * 16 + n16;
        const float* xr = x + (size_t)r * D + quad * 8;
#pragma unroll
        for (int ks = 0; ks < 4; ++ks) {
            float4 a = *(const float4*)(xr + ks * 32);
            float4 b = *(const float4*)(xr + ks * 32 + 4);
            float f[8] = {a.x, a.y, a.z, a.w, b.x, b.y, b.z, b.w};
            half8 h;
#pragma unroll
            for (int j = 0; j < 8; ++j) h[j] = (_Float16)f[j];
            Ah[rt][ks] = h;
        }
    }

    // best-2 (max of dot - c2/2) per slot k = rt*4+reg
    float b1[8], b2[8];
    int   j1_[8], j2_[8];
#pragma unroll
    for (int k = 0; k < 8; ++k) { b1[k] = -3.4e38f; b2[k] = -3.4e38f; j1_[k] = 0; j2_[k] = 0; }

    const char* gh = (const char*)wh + (size_t)half * CHUNKS_PER_HALF * 32768;

    // prologue: stage chunk 0 into buf0 (4 async16 per thread: 512*4*16B = 32 KB)
#pragma unroll
    for (int i = 0; i < 4; ++i) {
        int seg = w + i * 8;                           // wave-uniform, 0..31
        async_lds16(gh + seg * 1024 + L * 16, lds + seg * 1024);
    }
    __syncthreads();

    for (int ci = 0; ci < CHUNKS_PER_HALF; ++ci) {
        const char* cur = lds + (ci & 1) * 32768;
        // prefetch next chunk (no wait — lands during compute below)
        if (ci + 1 < CHUNKS_PER_HALF) {
            const char* gn = gh + (ci + 1) * 32768;
            char* nxt = lds + ((ci + 1) & 1) * 32768;
#pragma unroll
            for (int i = 0; i < 4; ++i) {
                int seg = w + i * 8;
                async_lds16(gn + seg * 1024 + L * 16, nxt + seg * 1024);
            }
        }

        const int kbase = (half * CHUNKS_PER_HALF + ci) * CHUNK_C + chalf * 64;
        float c2v[4];
#pragma unroll
        for (int ct = 0; ct < 4; ++ct) c2v[ct] = c2n[kbase + ct * 16 + n16];

        floatx4 acc[2][4];
#pragma unroll
        for (int rt = 0; rt < 2; ++rt)
#pragma unroll
            for (int ct = 0; ct < 4; ++ct)
                acc[rt][ct] = (floatx4){c2v[ct], c2v[ct], c2v[ct], c2v[ct]};

#pragma unroll
        for (int ks = 0; ks < 4; ++ks) {
            const half8* pb = (const half8*)cur + (ks * 4 + quad) * 128 + chalf * 64 + n16;
#pragma unroll
            for (int ct = 0; ct < 4; ++ct) {
                half8 Bf = pb[ct * 16];
                acc[0][ct] = __builtin_amdgcn_mfma_f32_16x16x32_f16(Ah[0][ks], Bf, acc[0][ct], 0, 0, 0);
                acc[1][ct] = __builtin_amdgcn_mfma_f32_16x16x32_f16(Ah[1][ks], Bf, acc[1][ct], 0, 0, 0);
            }
        }

        // quad-reduce over ct (same row), then best-2 insert per slot.
        int i0 = kbase + n16;
#pragma unroll
        for (int rt = 0; rt < 2; ++rt)
#pragma unroll
            for (int reg = 0; reg < 4; ++reg) {
                float s0 = acc[rt][0][reg], s1 = acc[rt][1][reg];
                float s2 = acc[rt][2][reg], s3 = acc[rt][3][reg];
                bool g01 = s1 > s0, g23 = s3 > s2;
                float m01 = g01 ? s1 : s0;  int x01 = g01 ? i0 + 16 : i0;
                float m23 = g23 ? s3 : s2;  int x23 = g23 ? i0 + 48 : i0 + 32;
                bool gq = m23 > m01;
                float v  = gq ? m23 : m01;  int vi = gq ? x23 : x01;
                int k = rt * 4 + reg;
                bool bet1 = v > b1[k];
                bool bet2 = v > b2[k];
                float nb2 = bet1 ? b1[k] : (bet2 ? v : b2[k]);
                int   nj2 = bet1 ? j1_[k] : (bet2 ? vi : j2_[k]);
                b1[k]  = bet1 ? v : b1[k];
                j1_[k] = bet1 ? vi : j1_[k];
                b2[k]  = nb2;
                j2_[k] = nj2;
            }

        __syncthreads();   // prefetch drained (free) + all waves done reading cur
    }

    int* candL = (int*)lds;       // [128 rows][8 candidates] — buffers are dead now

    // merge sorted best-2 (max) across 8-lane n16 groups
#pragma unroll
    for (int k = 0; k < 8; ++k) {
        float v1 = b1[k], v2 = b2[k];
        int   p1 = j1_[k], p2 = j2_[k];
#pragma unroll
        for (int m = 1; m < 8; m <<= 1) {
            float o1 = __shfl_xor(v1, m, 64), o2 = __shfl_xor(v2, m, 64);
            int   q1 = __shfl_xor(p1, m, 64), q2 = __shfl_xor(p2, m, 64);
            bool firstMine = (v1 > o1) || (v1 == o1 && p1 < q1);
            float nv1 = firstMine ? v1 : o1;  int np1 = firstMine ? p1 : q1;
            float cb  = firstMine ? o1 : v1;  int cpi = firstMine ? q1 : p1;  // loser of firsts
            float ob  = firstMine ? v2 : o2;  int obi = firstMine ? p2 : q2;  // winner's own 2nd
            bool secOwn = (ob > cb) || (ob == cb && obi < cpi);
            v1 = nv1; p1 = np1;
            v2 = secOwn ? ob : cb;  p2 = secOwn ? obi : cpi;
        }
        if ((n16 & 7) == 0) {
            int rloc = rq * 32 + (k >> 2) * 16 + quad * 4 + (k & 3);
            int g = chalf * 2 + (n16 >> 3);
            candL[rloc * 8 + g * 2 + 0] = p1;
            candL[rloc * 8 + g * 2 + 1] = p2;
        }
    }
    __syncthreads();

    // exact fp32 refine: 8 candidates/row, 2 per thread (128 rows x 4 threads)
    {
        int r = t >> 2, p = t & 3;
        int ixa = candL[r * 8 + p * 2 + 0];
        int ixb = candL[r * 8 + p * 2 + 1];
        const float4* xr4 = (const float4*)(x + (size_t)(gr0 + r) * D);
        const float4* ca4 = (const float4*)(centers + (size_t)ixa * D);
        const float4* cb4 = (const float4*)(centers + (size_t)ixb * D);
        float dota = 0.f, dotb = 0.f, x2s = 0.f, c2a = 0.f, c2b = 0.f;
#pragma unroll
        for (int d4 = 0; d4 < 32; ++d4) {
            float4 xv = xr4[d4], av = ca4[d4], bv = cb4[d4];
            dota = fmaf(xv.x, av.x, dota); dota = fmaf(xv.y, av.y, dota);
            dota = fmaf(xv.z, av.z, dota); dota = fmaf(xv.w, av.w, dota);
            dotb = fmaf(xv.x, bv.x, dotb); dotb = fmaf(xv.y, bv.y, dotb);
            dotb = fmaf(xv.z, bv.z, dotb); dotb = fmaf(xv.w, bv.w, dotb);
            x2s = fmaf(xv.x, xv.x, x2s); x2s = fmaf(xv.y, xv.y, x2s);
            x2s = fmaf(xv.z, xv.z, x2s); x2s = fmaf(xv.w, xv.w, x2s);
            c2a = fmaf(av.x, av.x, c2a); c2a = fmaf(av.y, av.y, c2a);
            c2a = fmaf(av.z, av.z, c2a); c2a = fmaf(av.w, av.w, c2a);
            c2b = fmaf(bv.x, bv.x, c2b); c2b = fmaf(bv.y, bv.y, c2b);
            c2b = fmaf(bv.z, bv.z, c2b); c2b = fmaf(bv.w, bv.w, c2b);
        }
        float sqa = x2s + c2a - 2.f * dota;
        float sqb = x2s + c2b - 2.f * dotb;
        bool aw = (sqa < sqb) || (sqa == sqb && ixa < ixb);
        float sq = aw ? sqa : sqb;
        int   ix = aw ? ixa : ixb;
#pragma unroll
        for (int m = 1; m < 4; m <<= 1) {
            float osq = __shfl_xor(sq, m, 64);
            int   oix = __shfl_xor(ix, m, 64);
            if (osq < sq || (osq == sq && oix < ix)) { sq = osq; ix = oix; }
        }
        if (p == 0) {
            ws_sq[(size_t)half * BATCH + gr0 + r] = sq;
            ws_ix[(size_t)half * BATCH + gr0 + r] = ix;
        }
    }
}

// ---- final merge + outputs: one thread per (row, d4), 32 threads/row ----
__global__ __launch_bounds__(256) void final_kernel(
    const float* __restrict__ x, const float* __restrict__ centers,
    const float* __restrict__ ws_sq, const int* __restrict__ ws_ix,
    float* __restrict__ out) {
    int g = blockIdx.x * 256 + threadIdx.x;   // 0 .. BATCH*32-1
    int row = g >> 5, d4 = g & 31;

    float sqa = ws_sq[row],         sqb = ws_sq[BATCH + row];
    int   ixa = ws_ix[row],         ixb = ws_ix[BATCH + row];
    // half-0 indices are all lower, so ties resolve to half-0
    bool aw = (sqa <= sqb);
    float sq = aw ? sqa : sqb;
    int   ix = aw ? ixa : ixb;

    float* out_clu = out + (size_t)BATCH * D;
    float* out_md  = out_clu + BATCH;
    float* out_cls = out_md + BATCH;
    if (d4 == 0) {
        out_md[row]  = sqrtf(fmaxf(sq, 0.f));
        out_clu[row] = (float)(ix & (KC - 1));
        out_cls[row] = (float)(ix >> 6);
    }

    float4 cv = ((const float4*)centers)[(size_t)ix * 32 + d4];
    float4 xv = ((const float4*)x)[(size_t)row * 32 + d4];
    float4 o;
    o.x = xv.x + (cv.x - xv.x);
    o.y = xv.y + (cv.y - xv.y);
    o.z = xv.z + (cv.z - xv.z);
    o.w = xv.w + (cv.w - xv.w);
    ((float4*)out)[(size_t)row * 32 + d4] = o;
}

extern "C" void kernel_launch(void* const* d_in, const int* in_sizes, int n_in,
                              void* d_out, int out_size, void* d_ws, size_t ws_size,
                              hipStream_t stream) {
    const float* x       = (const float*)d_in[0];
    const float* centers = (const float*)d_in[1];
    // d_in[2] = labels (int64) — unused by the forward computation
    float* out = (float*)d_out;

    _Float16* wh    = (_Float16*)d_ws;                  // K*D halves, chunk-major
    float*    c2n   = (float*)(wh + (size_t)K * D);     // K floats
    float*    ws_sq = c2n + K;                          // 2*BATCH floats
    int*      ws_ix = (int*)(ws_sq + HALVES * BATCH);   // 2*BATCH ints

    pack_kernel<<<(K * 16) / 256, 256, 0, stream>>>(centers, wh, c2n);
    dim3 grid(BATCH / ROWS_PER_BLOCK, HALVES);
    dist_kernel<<<grid, 512, 0, stream>>>(x, centers, wh, c2n, ws_sq, ws_ix);
    final_kernel<<<(BATCH * 32) / 256, 256, 0, stream>>>(x, centers, ws_sq, ws_ix, out);
}